// Round 2
// 528.165 us; speedup vs baseline: 1.0336x; 1.0336x over previous
//
#include <hip/hip_runtime.h>

#define DIM 128
#define GAMMA 12.0f
#define SCAN_BLOCK 256
#define SCAN_ELEMS 1024   // 4 elements per thread

// --- Phase 1: histogram of in-degree per dst node + per-edge rank ---
// rank[e] = position of edge e within its dst bucket (order = atomic arrival).
__global__ __launch_bounds__(256) void hist_rank_kernel(const int* __restrict__ dst,
                                                        int* __restrict__ cnt,
                                                        int* __restrict__ rank, int E) {
    int e = blockIdx.x * (int)blockDim.x + (int)threadIdx.x;
    if (e < E) rank[e] = atomicAdd(&cnt[dst[e]], 1);
}

// --- Phase 2a: per-block totals of cnt ---
__global__ __launch_bounds__(SCAN_BLOCK) void scan_reduce_kernel(
    const int* __restrict__ cnt, int* __restrict__ blockSums, int N) {
    int b = blockIdx.x, t = threadIdx.x;
    int base = b * SCAN_ELEMS + t * 4;
    int s = 0;
    #pragma unroll
    for (int j = 0; j < 4; ++j) {
        int i = base + j;
        if (i < N) s += cnt[i];
    }
    #pragma unroll
    for (int off = 32; off > 0; off >>= 1) s += __shfl_down(s, off, 64);
    __shared__ int wsum[SCAN_BLOCK / 64];
    if ((t & 63) == 0) wsum[t >> 6] = s;
    __syncthreads();
    if (t == 0) {
        int tot = 0;
        #pragma unroll
        for (int w = 0; w < SCAN_BLOCK / 64; ++w) tot += wsum[w];
        blockSums[b] = tot;
    }
}

// --- Phase 2b: exclusive scan of the block sums (B <= 256, one block) ---
__global__ __launch_bounds__(SCAN_BLOCK) void scan_spine_kernel(
    int* __restrict__ blockSums, int B) {
    __shared__ int sh[SCAN_BLOCK];
    int t = threadIdx.x;
    int v = (t < B) ? blockSums[t] : 0;
    sh[t] = v;
    __syncthreads();
    for (int off = 1; off < SCAN_BLOCK; off <<= 1) {
        int u = (t >= off) ? sh[t - off] : 0;
        __syncthreads();
        sh[t] += u;
        __syncthreads();
    }
    if (t < B) blockSums[t] = sh[t] - v;   // exclusive
}

// --- Phase 2c: per-block rescan; writes offs[] (exclusive prefix of cnt) ---
__global__ __launch_bounds__(SCAN_BLOCK) void scan_final_kernel(
    const int* __restrict__ blockSums, const int* __restrict__ cnt,
    int* __restrict__ offs, int N) {
    __shared__ int sh[SCAN_BLOCK];
    int b = blockIdx.x, t = threadIdx.x;
    int base = b * SCAN_ELEMS + t * 4;
    int v[4];
    int s = 0;
    #pragma unroll
    for (int j = 0; j < 4; ++j) {
        int i = base + j;
        v[j] = (i < N) ? cnt[i] : 0;
        s += v[j];
    }
    sh[t] = s;
    __syncthreads();
    for (int off = 1; off < SCAN_BLOCK; off <<= 1) {
        int u = (t >= off) ? sh[t - off] : 0;
        __syncthreads();
        sh[t] += u;
        __syncthreads();
    }
    int run = blockSums[b] + sh[t] - s;    // exclusive prefix for this thread
    #pragma unroll
    for (int j = 0; j < 4; ++j) {
        int i = base + j;
        if (i < N) offs[i] = run;
        run += v[j];
    }
}

// --- Phase 3: deterministic bucket write (NO atomics). Packs (e, src[e])
// so the node kernel skips one dependent-load level. ---
__global__ __launch_bounds__(256) void scatter_pack_kernel(
    const int* __restrict__ dst, const int* __restrict__ src,
    const int* __restrict__ rank, const int* __restrict__ offs,
    int2* __restrict__ sorted2, int E) {
    int e = blockIdx.x * (int)blockDim.x + (int)threadIdx.x;
    if (e < E) {
        int d = dst[e];
        sorted2[offs[d] + rank[e]] = make_int2(e, src[e]);
    }
}

// --- Phase 4: one wave per dst node, 4 edges in flight per wave.
// Lanes split into 4 groups of 16; group g takes edges k = start+g, step 4.
// Lane gl of a group owns float4 indices gl and gl+16 (dims gl*4.. and
// (gl+16)*4..) so every 16-lane load/store of a 512 B row is coalesced. ---
__global__ __launch_bounds__(256) void node_kernel(
    const float* __restrict__ node_emb,
    const float* __restrict__ edge_emb,
    const int2* __restrict__ sorted2,
    const int* __restrict__ offs,
    float* __restrict__ out,
    int N, int E)
{
    int wave = (blockIdx.x * (int)blockDim.x + (int)threadIdx.x) >> 6;
    int lane = (int)threadIdx.x & 63;
    if (wave >= N) return;

    int g  = lane >> 4;          // edge slot 0..3
    int gl = lane & 15;          // lane within group: owns float4 gl and gl+16

    int start = offs[wave];
    int end   = (wave + 1 < N) ? offs[wave + 1] : E;

    const float4* tp = (const float4*)(node_emb + (size_t)wave * DIM);
    float4 t0 = tp[gl];
    float4 t1 = tp[gl + 16];

    float4 a0 = make_float4(0.f, 0.f, 0.f, 0.f);
    float4 a1 = make_float4(0.f, 0.f, 0.f, 0.f);

    int k = start + g;
    int2 es = (k < end) ? sorted2[k] : make_int2(0, 0);
    while (k < end) {
        int kn = k + 4;
        int2 esn = (kn < end) ? sorted2[kn] : es;   // prefetch next slot

        const float4* hp = (const float4*)(node_emb + (size_t)es.y * DIM);
        const float4* rp = (const float4*)(edge_emb + (size_t)es.x * DIM);
        float4 h0 = hp[gl],      h1 = hp[gl + 16];
        float4 r0 = rp[gl],      r1 = rp[gl + 16];

        float4 x0, x1;
        x0.x = h0.x + r0.x; x0.y = h0.y + r0.y; x0.z = h0.z + r0.z; x0.w = h0.w + r0.w;
        x1.x = h1.x + r1.x; x1.y = h1.y + r1.y; x1.z = h1.z + r1.z; x1.w = h1.w + r1.w;

        float d0, sq;
        d0 = x0.x - t0.x; sq  = d0 * d0;
        d0 = x0.y - t0.y; sq += d0 * d0;
        d0 = x0.z - t0.z; sq += d0 * d0;
        d0 = x0.w - t0.w; sq += d0 * d0;
        d0 = x1.x - t1.x; sq += d0 * d0;
        d0 = x1.y - t1.y; sq += d0 * d0;
        d0 = x1.z - t1.z; sq += d0 * d0;
        d0 = x1.w - t1.w; sq += d0 * d0;

        // reduce across the 16 lanes of this group (xor offsets < 16)
        #pragma unroll
        for (int off = 8; off > 0; off >>= 1)
            sq += __shfl_xor(sq, off, 64);

        float score = 1.0f / (1.0f + expf(sqrtf(sq) - GAMMA));
        a0.x += score * x0.x; a0.y += score * x0.y; a0.z += score * x0.z; a0.w += score * x0.w;
        a1.x += score * x1.x; a1.y += score * x1.y; a1.z += score * x1.z; a1.w += score * x1.w;

        es = esn; k = kn;
    }

    // combine the 4 groups (lanes gl, gl+16, gl+32, gl+48 hold the same dims)
    #pragma unroll
    for (int off = 16; off <= 32; off <<= 1) {
        a0.x += __shfl_xor(a0.x, off, 64); a0.y += __shfl_xor(a0.y, off, 64);
        a0.z += __shfl_xor(a0.z, off, 64); a0.w += __shfl_xor(a0.w, off, 64);
        a1.x += __shfl_xor(a1.x, off, 64); a1.y += __shfl_xor(a1.y, off, 64);
        a1.z += __shfl_xor(a1.z, off, 64); a1.w += __shfl_xor(a1.w, off, 64);
    }

    if (g == 0) {
        float4* op = (float4*)(out + (size_t)wave * DIM);
        op[gl]      = a0;
        op[gl + 16] = a1;
    }
}

extern "C" void kernel_launch(void* const* d_in, const int* in_sizes, int n_in,
                              void* d_out, int out_size, void* d_ws, size_t ws_size,
                              hipStream_t stream) {
    const float* node_emb = (const float*)d_in[0];
    const float* edge_emb = (const float*)d_in[1];
    const int*   src      = (const int*)d_in[2];
    const int*   dst      = (const int*)d_in[3];
    float*       out      = (float*)d_out;

    int E = in_sizes[2];
    int N = out_size / DIM;
    int B = (N + SCAN_ELEMS - 1) / SCAN_ELEMS;   // 98 for N=100000

    // Workspace: sorted2[E] (int2, 8B-aligned at base) | cnt[N] | offs[N] |
    //            rank[E] | blockSums[SCAN_BLOCK]
    int2* sorted2   = (int2*)d_ws;
    int*  cnt       = (int*)(sorted2 + E);
    int*  offs      = cnt + N;
    int*  rank      = offs + N;
    int*  blockSums = rank + E;

    hipMemsetAsync(cnt, 0, (size_t)N * sizeof(int), stream);
    hist_rank_kernel<<<(E + 255) / 256, 256, 0, stream>>>(dst, cnt, rank, E);
    scan_reduce_kernel<<<B, SCAN_BLOCK, 0, stream>>>(cnt, blockSums, N);
    scan_spine_kernel<<<1, SCAN_BLOCK, 0, stream>>>(blockSums, B);
    scan_final_kernel<<<B, SCAN_BLOCK, 0, stream>>>(blockSums, cnt, offs, N);
    scatter_pack_kernel<<<(E + 255) / 256, 256, 0, stream>>>(dst, src, rank, offs,
                                                             sorted2, E);

    dim3 grid(((size_t)N * 64 + 255) / 256);
    node_kernel<<<grid, 256, 0, stream>>>(node_emb, edge_emb, sorted2, offs,
                                          out, N, E);
}